// Round 7
// baseline (139.658 us; speedup 1.0000x reference)
//
#include <hip/hip_runtime.h>
#include <hip/hip_bf16.h>

#define IH   48
#define IW   48
#define CH   64
#define KS   7
#define LN_EPS 1e-5f
#define QSCALE 0.35355339059327373f
#define L2E    1.4426950408889634f

#define TSH  6                   /* tile rows */
#define TSW  8                   /* tile cols */
#define TPX  48                  /* tile pixels */
#define HSH  12                  /* halo rows = TSH+6 */
#define HSW  14                  /* halo cols = TSW+6 */
#define HP   168                 /* halo pixels */
#define KVS  136                 /* kv LDS row stride bf16 (272 B) */
#define AOS  72                  /* q / attn-out LDS row stride bf16 (144 B) */
#define RPBN 1352                /* rpb floats: 8*13*13 */

typedef __bf16 bf16_t;
typedef bf16_t bf16x8 __attribute__((ext_vector_type(8)));
typedef float  f32x4  __attribute__((ext_vector_type(4)));
typedef float  f32x2  __attribute__((ext_vector_type(2)));

__device__ __forceinline__ float bflo(unsigned u) { union { unsigned i; float f; } v; v.i = u << 16; return v.f; }
__device__ __forceinline__ float bfhi(unsigned u) { union { unsigned i; float f; } v; v.i = u & 0xffff0000u; return v.f; }
__device__ __forceinline__ f32x2 unp2(unsigned u) { f32x2 r; r.x = bflo(u); r.y = bfhi(u); return r; }

__device__ __forceinline__ bf16x8 pack_bf16x8(float4 lo, float4 hi) {
    bf16x8 r;
    r[0] = (bf16_t)lo.x; r[1] = (bf16_t)lo.y; r[2] = (bf16_t)lo.z; r[3] = (bf16_t)lo.w;
    r[4] = (bf16_t)hi.x; r[5] = (bf16_t)hi.y; r[6] = (bf16_t)hi.z; r[7] = (bf16_t)hi.w;
    return r;
}

// r7: occupancy data r1-r6 shows ONE block/CU resident regardless of LDS size
// (OccupancyPercent == block_waves/32 every round) -> we ran at 2.25 waves/SIMD.
// Restructure: 48-px tile, 768-thread block (12 waves/CU = 3/SIMD), grid 768 =
// exactly 3 blocks/CU of work (balanced at either 1- or 2-block residency).
// Phase B: 2 threads per (pixel,head), split by window-COLUMN PARITY (cols
// {0,2,4,6} / {1,3,5}); parity folds into the base pointer so every tap keeps
// a compile-time ds offset; <=28 taps/thread (was 49); one 9-shuffle pair
// combine at the end. r6 sched_barrier reverted (regressed 49->62us).
__global__ __launch_bounds__(768, 3) void fused_na_kernel(
        const float* __restrict__ x,
        const float* __restrict__ w,      // qkv_w [192][64]
        const float* __restrict__ b,      // qkv_b [192]
        const float* __restrict__ rpb,
        const float* __restrict__ pw,     // proj_w [64][64]
        const float* __restrict__ pb,
        const float* __restrict__ g,
        const float* __restrict__ beta,
        float* __restrict__ out) {
    __shared__ __align__(16) __hip_bfloat16 kv[HP * KVS];    // 45,696 B
    __shared__ __align__(16) __hip_bfloat16 qao[TPX * AOS];  //  6,912 B
    __shared__ __align__(16) float rpbl[RPBN];               //  5,408 B

    const int blk  = blockIdx.x;         // 0..767
    const int n    = blk & 15;           // image
    const int tile = blk >> 4;           // 0..47
    const int i0   = (tile / 6) * TSH;   // 8 row-tiles
    const int j0   = (tile % 6) * TSW;   // 6 col-tiles
    int h0 = i0 - 3; h0 = h0 < 0 ? 0 : (h0 > IH - HSH ? IH - HSH : h0);
    int w0 = j0 - 3; w0 = w0 < 0 ? 0 : (w0 > IW - HSW ? IW - HSW : w0);
    const int tid = threadIdx.x;
    const size_t img = (size_t)n * (IH * IW);

    // ---- rpb -> LDS (coalesced, 2 dwords/thread) ----
    for (int idx = tid; idx < RPBN; idx += 768) rpbl[idx] = rpb[idx];

    // ---------------- phase A: QKV -> LDS --------------------------------
    // 25 m-tile units: K halo (11) + V halo (11) + Q interior (3), spread
    // round-robin over 12 waves.
    {
        const int wv = tid >> 6;         // 0..11
        const int l  = tid & 63;
        const int m  = l & 15;
        const int kg = l >> 4;

        for (int u = wv; u < 25; u += 12) {
            int grp, mt;
            if (u < 11)      { grp = 1; mt = u; }
            else if (u < 22) { grp = 2; mt = u - 11; }
            else             { grp = 0; mt = u - 22; }

            const int ch_base = grp * 64 + m * 4;
            const float4 bias4 = *(const float4*)(b + ch_base);
            const float scale = (grp == 0) ? (QSCALE * L2E) : 1.f;
            bf16x8 wb0[4], wb1[4];
            #pragma unroll
            for (int t = 0; t < 4; ++t) {
                const float* wr_ = w + (size_t)(ch_base + t) * CH + kg * 8;
                wb0[t] = pack_bf16x8(*(const float4*)(wr_),      *(const float4*)(wr_ + 4));
                wb1[t] = pack_bf16x8(*(const float4*)(wr_ + 32), *(const float4*)(wr_ + 36));
            }

            int hr, wc;
            if (grp == 0) {                      // Q: 48 px = 3 exact m-tiles
                const int px = mt * 16 + m;
                hr = i0 + (px >> 3); wc = j0 + (px & 7);
            } else {                             // K/V: 168 halo px, 11 m-tiles
                int hp = mt * 16 + m; if (hp > HP - 1) hp = HP - 1;  // clamped rows feed only masked D-rows
                hr = h0 + hp / HSW;  wc = w0 + hp % HSW;
            }
            const float* xr = x + (img + hr * IW + wc) * CH + kg * 8;
            const bf16x8 a0 = pack_bf16x8(*(const float4*)(xr),      *(const float4*)(xr + 4));
            const bf16x8 a1 = pack_bf16x8(*(const float4*)(xr + 32), *(const float4*)(xr + 36));

            float val[4][4];
            #pragma unroll
            for (int t = 0; t < 4; ++t) {
                f32x4 acc = {0.f, 0.f, 0.f, 0.f};
                acc = __builtin_amdgcn_mfma_f32_16x16x32_bf16(a0, wb0[t], acc, 0, 0, 0);
                acc = __builtin_amdgcn_mfma_f32_16x16x32_bf16(a1, wb1[t], acc, 0, 0, 0);
                const float bias = (t == 0) ? bias4.x : (t == 1) ? bias4.y : (t == 2) ? bias4.z : bias4.w;
                #pragma unroll
                for (int rr = 0; rr < 4; ++rr) val[t][rr] = (acc[rr] + bias) * scale;
            }
            #pragma unroll
            for (int rr = 0; rr < 4; ++rr) {
                const int pix = mt * 16 + kg * 4 + rr;
                union { ushort4 u; __hip_bfloat16 hh[4]; } pk;
                #pragma unroll
                for (int t = 0; t < 4; ++t) pk.hh[t] = __float2bfloat16(val[t][rr]);
                if (grp == 0) {
                    *reinterpret_cast<ushort4*>(qao + pix * AOS + m * 4) = pk.u;
                } else if (pix < HP) {
                    *reinterpret_cast<ushort4*>(kv + pix * KVS + (grp - 1) * 64 + m * 4) = pk.u;
                }
            }
        }
    }
    __syncthreads();

    // ---------------- phase B: 2 threads per (pixel,head) ----------------
    {
        const int half = tid & 1;            // window-column parity
        const int h    = (tid >> 1) & 7;
        const int px   = tid >> 4;           // 0..47
        const int i    = i0 + (px >> 3);
        const int j    = j0 + (px & 7);

        f32x2 q0[4];
        {
            const uint4 u = *reinterpret_cast<const uint4*>(qao + px * AOS + h * 8);
            q0[0] = unp2(u.x); q0[1] = unp2(u.y); q0[2] = unp2(u.z); q0[3] = unp2(u.w);
        }
        __syncthreads();                     // qao region reused for attn-out

        int si = i - 3;  si = si < 0 ? 0 : (si > IH - KS ? IH - KS : si);
        int sj = j - 3;  sj = sj < 0 ? 0 : (sj > IW - KS ? IW - KS : sj);
        const float* rpc2 = rpbl + h * (2*KS-1) * (2*KS-1)
                                 + (si - i + (KS-1)) * (2*KS-1) + (sj - j + (KS-1)) + half;
        const __hip_bfloat16* kvb = kv + ((si - h0) * HSW + (sj - w0) + half) * KVS + h * 8;

        float lr = 0.f;
        f32x2 a[4];
        #pragma unroll
        for (int d = 0; d < 4; ++d) a[d] = (f32x2){0.f, 0.f};

        // cols = 2*cc + half; half0: {0,2,4,6}, half1: {1,3,5}. All ds offsets
        // are compile-time constants relative to kvb.
        #pragma unroll
        for (int p = 0; p < KS; ++p) {
            #pragma unroll
            for (int cc = 0; cc < 4; ++cc) {
                if (cc == 3 && half) continue;   // col 7 doesn't exist for odd parity
                const uint4 kb = *reinterpret_cast<const uint4*>(kvb + (p * HSW + 2 * cc) * KVS);
                const uint4 vb = *reinterpret_cast<const uint4*>(kvb + (p * HSW + 2 * cc) * KVS + 64);
                const float bl = rpc2[p * (2*KS-1) + 2 * cc];

                f32x2 t = q0[0]*unp2(kb.x) + q0[1]*unp2(kb.y)
                        + q0[2]*unp2(kb.z) + q0[3]*unp2(kb.w);
                const float e = __builtin_amdgcn_exp2f(fmaf(bl, L2E, t.x + t.y));
                lr += e;
                a[0] += e * unp2(vb.x); a[1] += e * unp2(vb.y);
                a[2] += e * unp2(vb.z); a[3] += e * unp2(vb.w);
            }
        }

        // pair combine (partner = lane^1: same px,h, other parity)
        #pragma unroll
        for (int d = 0; d < 4; ++d) {
            a[d].x += __shfl_xor(a[d].x, 1, 64);
            a[d].y += __shfl_xor(a[d].y, 1, 64);
        }
        lr += __shfl_xor(lr, 1, 64);
        const float inv = 1.f / lr;

        // each thread writes its 4 channels (static select, no scratch)
        const f32x2 alo = half ? a[2] : a[0];
        const f32x2 ahi = half ? a[3] : a[1];
        union { uint2 u; __hip_bfloat16 hh[4]; } pk;
        pk.hh[0] = __float2bfloat16(alo.x * inv);
        pk.hh[1] = __float2bfloat16(alo.y * inv);
        pk.hh[2] = __float2bfloat16(ahi.x * inv);
        pk.hh[3] = __float2bfloat16(ahi.y * inv);
        *reinterpret_cast<uint2*>(qao + px * AOS + h * 8 + half * 4) = pk.u;
    }
    __syncthreads();

    // ---------------- phase C: proj + LN (waves 0-2, 3 exact m-tiles) ----
    if ((tid >> 6) < 3) {
        const int wv = tid >> 6;             // 0..2
        const int l  = tid & 63;
        const int m  = l & 15;
        const int kg = l >> 4;

        const __hip_bfloat16* ar = qao + (wv * 16 + m) * AOS + kg * 8;
        const bf16x8 a0 = *reinterpret_cast<const bf16x8*>(ar);
        const bf16x8 a1 = *reinterpret_cast<const bf16x8*>(ar + 32);

        const int ch_base = m * 4;
        const float4 bias4 = *(const float4*)(pb + ch_base);

        float val[4][4];                                   // [t][r], ch = m*4+t
        #pragma unroll
        for (int t = 0; t < 4; ++t) {
            const float* wr_ = pw + (size_t)(ch_base + t) * CH + kg * 8;  // permuted B row
            const bf16x8 b0 = pack_bf16x8(*(const float4*)(wr_),      *(const float4*)(wr_ + 4));
            const bf16x8 b1 = pack_bf16x8(*(const float4*)(wr_ + 32), *(const float4*)(wr_ + 36));
            f32x4 acc = {0.f, 0.f, 0.f, 0.f};
            acc = __builtin_amdgcn_mfma_f32_16x16x32_bf16(a0, b0, acc, 0, 0, 0);
            acc = __builtin_amdgcn_mfma_f32_16x16x32_bf16(a1, b1, acc, 0, 0, 0);
            const float bias = (t == 0) ? bias4.x : (t == 1) ? bias4.y : (t == 2) ? bias4.z : bias4.w;
            #pragma unroll
            for (int r = 0; r < 4; ++r) val[t][r] = acc[r] + bias;
        }

        float sm[4];
        #pragma unroll
        for (int r = 0; r < 4; ++r) sm[r] = val[0][r] + val[1][r] + val[2][r] + val[3][r];
        #pragma unroll
        for (int mask = 1; mask <= 8; mask <<= 1) {
            #pragma unroll
            for (int r = 0; r < 4; ++r) sm[r] += __shfl_xor(sm[r], mask, 64);
        }
        float mu[4];
        #pragma unroll
        for (int r = 0; r < 4; ++r) mu[r] = sm[r] * (1.f / 64.f);

        float qs[4];
        #pragma unroll
        for (int r = 0; r < 4; ++r) {
            float aa = val[0][r] - mu[r], bq = val[1][r] - mu[r];
            float c  = val[2][r] - mu[r], d  = val[3][r] - mu[r];
            qs[r] = aa * aa + bq * bq + c * c + d * d;
        }
        #pragma unroll
        for (int mask = 1; mask <= 8; mask <<= 1) {
            #pragma unroll
            for (int r = 0; r < 4; ++r) qs[r] += __shfl_xor(qs[r], mask, 64);
        }
        float rs[4];
        #pragma unroll
        for (int r = 0; r < 4; ++r) rs[r] = rsqrtf(qs[r] * (1.f / 64.f) + LN_EPS);

        const float4 g4  = *(const float4*)(g + ch_base);
        const float4 be4 = *(const float4*)(beta + ch_base);
        #pragma unroll
        for (int r = 0; r < 4; ++r) {
            const int pl = wv * 16 + kg * 4 + r;          // local pixel 0..47
            const int gi = i0 + (pl >> 3), gj = j0 + (pl & 7);
            float4 o;
            o.x = (val[0][r] - mu[r]) * rs[r] * g4.x + be4.x;
            o.y = (val[1][r] - mu[r]) * rs[r] * g4.y + be4.y;
            o.z = (val[2][r] - mu[r]) * rs[r] * g4.z + be4.z;
            o.w = (val[3][r] - mu[r]) * rs[r] * g4.w + be4.w;
            *reinterpret_cast<float4*>(out + (img + gi * IW + gj) * CH + ch_base) = o;
        }
    }
}

extern "C" void kernel_launch(void* const* d_in, const int* in_sizes, int n_in,
                              void* d_out, int out_size, void* d_ws, size_t ws_size,
                              hipStream_t stream) {
    const float* x      = (const float*)d_in[0];
    const float* qkv_w  = (const float*)d_in[1];
    const float* qkv_b  = (const float*)d_in[2];
    const float* proj_w = (const float*)d_in[3];
    const float* proj_b = (const float*)d_in[4];
    const float* rpb    = (const float*)d_in[5];
    const float* ln_g   = (const float*)d_in[6];
    const float* ln_b   = (const float*)d_in[7];
    float* out = (float*)d_out;

    fused_na_kernel<<<768, 768, 0, stream>>>(x, qkv_w, qkv_b, rpb,
                                             proj_w, proj_b, ln_g, ln_b, out);
}

// Round 8
// 112.221 us; speedup vs baseline: 1.2445x; 1.2445x over previous
//
#include <hip/hip_runtime.h>
#include <hip/hip_bf16.h>

#define IH   48
#define IW   48
#define CH   64
#define KS   7
#define LN_EPS 1e-5f
#define QSCALE 0.35355339059327373f
#define L2E    1.4426950408889634f

#define TSH  12                  /* tile rows */
#define TSW  12                  /* tile cols */
#define TPX  144                 /* tile pixels */
#define HSH  18                  /* halo rows = TSH+6 */
#define HSW  18                  /* halo cols = TSW+6 */
#define HP   324                 /* halo pixels */
#define KVS  136                 /* kv LDS row stride bf16 (272 B) */
#define AOS  72                  /* q / attn-out LDS row stride bf16 (144 B) */
#define RPBN 1352                /* rpb floats: 8*13*13 */

typedef __bf16 bf16_t;
typedef bf16_t bf16x8 __attribute__((ext_vector_type(8)));
typedef float  f32x4  __attribute__((ext_vector_type(4)));
typedef float  f32x2  __attribute__((ext_vector_type(2)));

__device__ __forceinline__ float bflo(unsigned u) { union { unsigned i; float f; } v; v.i = u << 16; return v.f; }
__device__ __forceinline__ float bfhi(unsigned u) { union { unsigned i; float f; } v; v.i = u & 0xffff0000u; return v.f; }
__device__ __forceinline__ f32x2 unp2(unsigned u) { f32x2 r; r.x = bflo(u); r.y = bfhi(u); return r; }

__device__ __forceinline__ bf16x8 pack_bf16x8(float4 lo, float4 hi) {
    bf16x8 r;
    r[0] = (bf16_t)lo.x; r[1] = (bf16_t)lo.y; r[2] = (bf16_t)lo.z; r[3] = (bf16_t)lo.w;
    r[4] = (bf16_t)hi.x; r[5] = (bf16_t)hi.y; r[6] = (bf16_t)hi.z; r[7] = (bf16_t)hi.w;
    return r;
}

// r8: empirical law from r1-r7: dur ~= (nblocks/256) * 24.5us, nearly
// independent of block content (4-12 waves, 25-49 taps/thread all identical
// per-slot time; 1 block/CU resident every round). Exploit: grid = EXACTLY
// 256 blocks (16 img x 16 12x12-tiles) = one residency round. 576 thr (9
// waves, r5's proven shape); phase B = r5's verified loop run exactly twice
// per thread (1152 units / 576 thr); phase A fuses K+V per unit (x halo read
// once, weights hoisted); phase C = 9 exact m-tiles / 9 waves. LDS 114 KB.
// Discriminator: ~27us confirms fixed-per-round cost; ~49us kills the law
// (then: MFMA-attention rewrite).
__global__ __launch_bounds__(576, 2) void fused_na_kernel(
        const float* __restrict__ x,
        const float* __restrict__ w,      // qkv_w [192][64]
        const float* __restrict__ b,      // qkv_b [192]
        const float* __restrict__ rpb,
        const float* __restrict__ pw,     // proj_w [64][64]
        const float* __restrict__ pb,
        const float* __restrict__ g,
        const float* __restrict__ beta,
        float* __restrict__ out) {
    __shared__ __align__(16) __hip_bfloat16 kv[HP * KVS];    // 88,128 B
    __shared__ __align__(16) __hip_bfloat16 qao[TPX * AOS];  // 20,736 B
    __shared__ __align__(16) float rpbl[RPBN];               //  5,408 B

    const int blk  = blockIdx.x;         // 0..255
    const int n    = blk & 15;           // image
    const int tile = blk >> 4;           // 0..15
    const int i0   = (tile >> 2) * TSH;  // 4 row-tiles
    const int j0   = (tile & 3) * TSW;   // 4 col-tiles
    int h0 = i0 - 3; h0 = h0 < 0 ? 0 : (h0 > IH - HSH ? IH - HSH : h0);
    int w0 = j0 - 3; w0 = w0 < 0 ? 0 : (w0 > IW - HSW ? IW - HSW : w0);
    const int tid = threadIdx.x;
    const size_t img = (size_t)n * (IH * IW);

    // ---- rpb -> LDS (coalesced, 3 dwords/thread) ----
    for (int idx = tid; idx < RPBN; idx += 576) rpbl[idx] = rpb[idx];

    // ---------------- phase A: QKV -> LDS --------------------------------
    // 30 units: 21 fused K+V halo m-tiles + 9 exact Q m-tiles, over 9 waves.
    // Every wave gets 2-3 KV units and exactly one Q unit.
    {
        const int wv = tid >> 6;         // 0..8
        const int l  = tid & 63;
        const int m  = l & 15;
        const int kg = l >> 4;

        // hoisted K/V weight fragments + biases (32 VGPR)
        bf16x8 wk0[4], wk1[4], wv0[4], wv1[4];
        #pragma unroll
        for (int t = 0; t < 4; ++t) {
            const float* wrk = w + (size_t)(64 + m * 4 + t) * CH + kg * 8;
            wk0[t] = pack_bf16x8(*(const float4*)(wrk),      *(const float4*)(wrk + 4));
            wk1[t] = pack_bf16x8(*(const float4*)(wrk + 32), *(const float4*)(wrk + 36));
            const float* wrv = w + (size_t)(128 + m * 4 + t) * CH + kg * 8;
            wv0[t] = pack_bf16x8(*(const float4*)(wrv),      *(const float4*)(wrv + 4));
            wv1[t] = pack_bf16x8(*(const float4*)(wrv + 32), *(const float4*)(wrv + 36));
        }
        const float4 biasK = *(const float4*)(b + 64 + m * 4);
        const float4 biasV = *(const float4*)(b + 128 + m * 4);

        for (int u = wv; u < 30; u += 9) {
            if (u < 21) {
                // ---- fused K+V halo unit: x loaded ONCE, 16 MFMA ----
                int hp = u * 16 + m; if (hp > HP - 1) hp = HP - 1;  // clamped A-rows feed only masked D-rows
                const int hr = h0 + hp / HSW;
                const int wc = w0 + hp % HSW;
                const float* xr = x + (img + hr * IW + wc) * CH + kg * 8;
                const bf16x8 a0 = pack_bf16x8(*(const float4*)(xr),      *(const float4*)(xr + 4));
                const bf16x8 a1 = pack_bf16x8(*(const float4*)(xr + 32), *(const float4*)(xr + 36));

                float valK[4][4], valV[4][4];
                #pragma unroll
                for (int t = 0; t < 4; ++t) {
                    f32x4 ak = {0.f, 0.f, 0.f, 0.f};
                    ak = __builtin_amdgcn_mfma_f32_16x16x32_bf16(a0, wk0[t], ak, 0, 0, 0);
                    ak = __builtin_amdgcn_mfma_f32_16x16x32_bf16(a1, wk1[t], ak, 0, 0, 0);
                    f32x4 av = {0.f, 0.f, 0.f, 0.f};
                    av = __builtin_amdgcn_mfma_f32_16x16x32_bf16(a0, wv0[t], av, 0, 0, 0);
                    av = __builtin_amdgcn_mfma_f32_16x16x32_bf16(a1, wv1[t], av, 0, 0, 0);
                    const float bk = (t == 0) ? biasK.x : (t == 1) ? biasK.y : (t == 2) ? biasK.z : biasK.w;
                    const float bv = (t == 0) ? biasV.x : (t == 1) ? biasV.y : (t == 2) ? biasV.z : biasV.w;
                    #pragma unroll
                    for (int rr = 0; rr < 4; ++rr) { valK[t][rr] = ak[rr] + bk; valV[t][rr] = av[rr] + bv; }
                }
                #pragma unroll
                for (int rr = 0; rr < 4; ++rr) {
                    const int pix = u * 16 + kg * 4 + rr;
                    if (pix < HP) {
                        union { ushort4 u4; __hip_bfloat16 hh[4]; } pk;
                        #pragma unroll
                        for (int t = 0; t < 4; ++t) pk.hh[t] = __float2bfloat16(valK[t][rr]);
                        *reinterpret_cast<ushort4*>(kv + pix * KVS + m * 4) = pk.u4;
                        #pragma unroll
                        for (int t = 0; t < 4; ++t) pk.hh[t] = __float2bfloat16(valV[t][rr]);
                        *reinterpret_cast<ushort4*>(kv + pix * KVS + 64 + m * 4) = pk.u4;
                    }
                }
            } else {
                // ---- Q unit: 9 exact m-tiles, no clamping ----
                const int mt = u - 21;
                const int px = mt * 16 + m;
                const int hr = i0 + px / TSW;
                const int wc = j0 + px % TSW;
                bf16x8 wq0[4], wq1[4];
                #pragma unroll
                for (int t = 0; t < 4; ++t) {
                    const float* wr_ = w + (size_t)(m * 4 + t) * CH + kg * 8;
                    wq0[t] = pack_bf16x8(*(const float4*)(wr_),      *(const float4*)(wr_ + 4));
                    wq1[t] = pack_bf16x8(*(const float4*)(wr_ + 32), *(const float4*)(wr_ + 36));
                }
                const float4 biasQ = *(const float4*)(b + m * 4);
                const float* xr = x + (img + hr * IW + wc) * CH + kg * 8;
                const bf16x8 a0 = pack_bf16x8(*(const float4*)(xr),      *(const float4*)(xr + 4));
                const bf16x8 a1 = pack_bf16x8(*(const float4*)(xr + 32), *(const float4*)(xr + 36));
                float val[4][4];
                #pragma unroll
                for (int t = 0; t < 4; ++t) {
                    f32x4 acc = {0.f, 0.f, 0.f, 0.f};
                    acc = __builtin_amdgcn_mfma_f32_16x16x32_bf16(a0, wq0[t], acc, 0, 0, 0);
                    acc = __builtin_amdgcn_mfma_f32_16x16x32_bf16(a1, wq1[t], acc, 0, 0, 0);
                    const float bias = (t == 0) ? biasQ.x : (t == 1) ? biasQ.y : (t == 2) ? biasQ.z : biasQ.w;
                    #pragma unroll
                    for (int rr = 0; rr < 4; ++rr) val[t][rr] = (acc[rr] + bias) * (QSCALE * L2E);
                }
                #pragma unroll
                for (int rr = 0; rr < 4; ++rr) {
                    const int pix = mt * 16 + kg * 4 + rr;
                    union { ushort4 u4; __hip_bfloat16 hh[4]; } pk;
                    #pragma unroll
                    for (int t = 0; t < 4; ++t) pk.hh[t] = __float2bfloat16(val[t][rr]);
                    *reinterpret_cast<ushort4*>(qao + pix * AOS + m * 4) = pk.u4;
                }
            }
        }
    }
    __syncthreads();

    // ---------------- phase B: per-(pixel,head) attention, 2 units/thread
    // rep 0 handles px 0..71 (and overwrites only those qao slots with ao);
    // rep 1 reads q of px 72..143 — disjoint, no barrier needed between reps.
    // q-read and ao-write of a pixel are done by the same 8 lanes of one wave
    // (in-order LDS pipe), so no intra-rep barrier either.
    for (int rep = 0; rep < 2; ++rep) {
        const int h  = tid & 7;
        const int px = (tid >> 3) + rep * 72;   // 0..143
        const int i  = i0 + px / TSW;
        const int j  = j0 + px % TSW;

        f32x2 q0[4];
        {
            const uint4 u = *reinterpret_cast<const uint4*>(qao + px * AOS + h * 8);
            q0[0] = unp2(u.x); q0[1] = unp2(u.y); q0[2] = unp2(u.z); q0[3] = unp2(u.w);
        }

        int si = i - 3;  si = si < 0 ? 0 : (si > IH - KS ? IH - KS : si);
        int sj = j - 3;  sj = sj < 0 ? 0 : (sj > IW - KS ? IW - KS : sj);
        const float* rpc = rpbl + h * (2*KS-1) * (2*KS-1)
                                + (si - i + (KS-1)) * (2*KS-1) + (sj - j + (KS-1));
        const __hip_bfloat16* kbase = kv + ((si - h0) * HSW + (sj - w0)) * KVS + h * 8;

        float lr = 0.f;
        f32x2 a[4];
        #pragma unroll
        for (int d = 0; d < 4; ++d) a[d] = (f32x2){0.f, 0.f};

        for (int p = 0; p < KS; ++p) {       // uniform 7 rows, no divergence
            const __hip_bfloat16* row = kbase + p * (HSW * KVS);
            uint4 kb[KS], vb[KS];
            #pragma unroll
            for (int qq = 0; qq < KS; ++qq) {
                kb[qq] = *reinterpret_cast<const uint4*>(row + qq * KVS);
                vb[qq] = *reinterpret_cast<const uint4*>(row + qq * KVS + 64);
            }
            float bl[KS];
            #pragma unroll
            for (int qq = 0; qq < KS; ++qq) bl[qq] = rpc[p * (2*KS-1) + qq];

            float s[KS];
            #pragma unroll
            for (int qq = 0; qq < KS; ++qq) {
                const f32x2 k0 = unp2(kb[qq].x), k1 = unp2(kb[qq].y);
                const f32x2 k2 = unp2(kb[qq].z), k3 = unp2(kb[qq].w);
                f32x2 t = q0[0]*k0 + q0[1]*k1 + q0[2]*k2 + q0[3]*k3;
                s[qq] = t.x + t.y;
            }
            float e[KS];
            #pragma unroll
            for (int qq = 0; qq < KS; ++qq)
                e[qq] = __builtin_amdgcn_exp2f(fmaf(bl[qq], L2E, s[qq]));

            #pragma unroll
            for (int qq = 0; qq < KS; ++qq) {
                const f32x2 v0 = unp2(vb[qq].x), v1 = unp2(vb[qq].y);
                const f32x2 v2 = unp2(vb[qq].z), v3 = unp2(vb[qq].w);
                lr += e[qq];
                a[0] += e[qq] * v0; a[1] += e[qq] * v1;
                a[2] += e[qq] * v2; a[3] += e[qq] * v3;
            }
        }
        const float inv = 1.f / lr;
        union { uint4 u; __hip_bfloat16 hh[8]; } pk;
        #pragma unroll
        for (int d = 0; d < 4; ++d) {
            pk.hh[2*d]   = __float2bfloat16(a[d].x * inv);
            pk.hh[2*d+1] = __float2bfloat16(a[d].y * inv);
        }
        *reinterpret_cast<uint4*>(qao + px * AOS + h * 8) = pk.u;
    }
    __syncthreads();

    // ---------------- phase C: proj + LN (9 waves, 9 exact m-tiles) ------
    {
        const int wv = tid >> 6;             // 0..8
        const int l  = tid & 63;
        const int m  = l & 15;
        const int kg = l >> 4;

        const __hip_bfloat16* ar = qao + (wv * 16 + m) * AOS + kg * 8;
        const bf16x8 a0 = *reinterpret_cast<const bf16x8*>(ar);
        const bf16x8 a1 = *reinterpret_cast<const bf16x8*>(ar + 32);

        const int ch_base = m * 4;
        const float4 bias4 = *(const float4*)(pb + ch_base);

        float val[4][4];                                   // [t][r], ch = m*4+t
        #pragma unroll
        for (int t = 0; t < 4; ++t) {
            const float* wr_ = pw + (size_t)(ch_base + t) * CH + kg * 8;  // permuted B row
            const bf16x8 b0 = pack_bf16x8(*(const float4*)(wr_),      *(const float4*)(wr_ + 4));
            const bf16x8 b1 = pack_bf16x8(*(const float4*)(wr_ + 32), *(const float4*)(wr_ + 36));
            f32x4 acc = {0.f, 0.f, 0.f, 0.f};
            acc = __builtin_amdgcn_mfma_f32_16x16x32_bf16(a0, b0, acc, 0, 0, 0);
            acc = __builtin_amdgcn_mfma_f32_16x16x32_bf16(a1, b1, acc, 0, 0, 0);
            const float bias = (t == 0) ? bias4.x : (t == 1) ? bias4.y : (t == 2) ? bias4.z : bias4.w;
            #pragma unroll
            for (int r = 0; r < 4; ++r) val[t][r] = acc[r] + bias;
        }

        float sm[4];
        #pragma unroll
        for (int r = 0; r < 4; ++r) sm[r] = val[0][r] + val[1][r] + val[2][r] + val[3][r];
        #pragma unroll
        for (int mask = 1; mask <= 8; mask <<= 1) {
            #pragma unroll
            for (int r = 0; r < 4; ++r) sm[r] += __shfl_xor(sm[r], mask, 64);
        }
        float mu[4];
        #pragma unroll
        for (int r = 0; r < 4; ++r) mu[r] = sm[r] * (1.f / 64.f);

        float qs[4];
        #pragma unroll
        for (int r = 0; r < 4; ++r) {
            float aa = val[0][r] - mu[r], bq = val[1][r] - mu[r];
            float c  = val[2][r] - mu[r], d  = val[3][r] - mu[r];
            qs[r] = aa * aa + bq * bq + c * c + d * d;
        }
        #pragma unroll
        for (int mask = 1; mask <= 8; mask <<= 1) {
            #pragma unroll
            for (int r = 0; r < 4; ++r) qs[r] += __shfl_xor(qs[r], mask, 64);
        }
        float rs[4];
        #pragma unroll
        for (int r = 0; r < 4; ++r) rs[r] = rsqrtf(qs[r] * (1.f / 64.f) + LN_EPS);

        const float4 g4  = *(const float4*)(g + ch_base);
        const float4 be4 = *(const float4*)(beta + ch_base);
        #pragma unroll
        for (int r = 0; r < 4; ++r) {
            const int pl = wv * 16 + kg * 4 + r;          // local pixel 0..143
            const int gi = i0 + pl / TSW, gj = j0 + pl % TSW;
            float4 o;
            o.x = (val[0][r] - mu[r]) * rs[r] * g4.x + be4.x;
            o.y = (val[1][r] - mu[r]) * rs[r] * g4.y + be4.y;
            o.z = (val[2][r] - mu[r]) * rs[r] * g4.z + be4.z;
            o.w = (val[3][r] - mu[r]) * rs[r] * g4.w + be4.w;
            *reinterpret_cast<float4*>(out + (img + gi * IW + gj) * CH + ch_base) = o;
        }
    }
}

extern "C" void kernel_launch(void* const* d_in, const int* in_sizes, int n_in,
                              void* d_out, int out_size, void* d_ws, size_t ws_size,
                              hipStream_t stream) {
    const float* x      = (const float*)d_in[0];
    const float* qkv_w  = (const float*)d_in[1];
    const float* qkv_b  = (const float*)d_in[2];
    const float* proj_w = (const float*)d_in[3];
    const float* proj_b = (const float*)d_in[4];
    const float* rpb    = (const float*)d_in[5];
    const float* ln_g   = (const float*)d_in[6];
    const float* ln_b   = (const float*)d_in[7];
    float* out = (float*)d_out;

    fused_na_kernel<<<256, 576, 0, stream>>>(x, qkv_w, qkv_b, rpb,
                                             proj_w, proj_b, ln_g, ln_b, out);
}